// Round 1
// baseline (230.434 us; speedup 1.0000x reference)
//
#include <hip/hip_runtime.h>
#include <math.h>

// Problem constants (setup_inputs is fixed): 512x512 image, A=512 angles,
// D=512 detectors, S=256 sampling points, step_size=1.
#define IMG 512
#define A_N 512
#define D_N 512
#define S_N 256

// ---------------------------------------------------------------------------
// Transpose 512x512 fp32 image into workspace (for the per-angle axis-swap
// trick: sample from whichever layout keeps the wave's gather footprint
// row-minimal).
// ---------------------------------------------------------------------------
__global__ __launch_bounds__(256)
void transpose_kernel(const float* __restrict__ in, float* __restrict__ out) {
    __shared__ float tile[32][33];           // +1 pad: no LDS bank conflicts
    const int bx = blockIdx.x & 15;          // 16x16 tiles of 32x32
    const int by = blockIdx.x >> 4;
    const int tx = threadIdx.x & 31;
    const int ty = threadIdx.x >> 5;         // 0..7
    const int x0 = bx * 32, y0 = by * 32;
    #pragma unroll
    for (int i = 0; i < 4; ++i) {
        const int r = ty + i * 8;
        tile[r][tx] = in[(y0 + r) * IMG + (x0 + tx)];
    }
    __syncthreads();
    #pragma unroll
    for (int i = 0; i < 4; ++i) {
        const int r = ty + i * 8;            // original column index offset
        out[(x0 + r) * IMG + (y0 + tx)] = tile[tx][r];
    }
}

// ---------------------------------------------------------------------------
// Radon forward projection. One thread per (angle a, detector d) output.
// Lanes map to consecutive detectors (tid & 511) so a wave's 64 gathers lie
// 1 px apart along the rotated detector axis -> maximal cache-line sharing.
// ---------------------------------------------------------------------------
__global__ __launch_bounds__(256)
void radon_fwd(const float* __restrict__ img, const float* __restrict__ imgT,
               const int use_t, float* __restrict__ out) {
    const int tid = blockIdx.x * 256 + threadIdx.x;
    const int d = tid & (D_N - 1);
    const int a = tid >> 9;

    const float PI  = 3.14159265358979323846f;
    const float SQ2 = 1.41421356237309504880f;

    // angles = linspace(0,pi,512) + pi/2 ; sy = -sqrt(2)
    const float ang = fmaf((float)a, PI / 511.0f, PI * 0.5f);
    float sa, ca;
    sincosf(ang, &sa, &ca);

    // sx = linspace(-1,1,512)[d] (step_size=1, det spacing = 1 px)
    const float sx  = fmaf((float)d, 2.0f / 511.0f, -1.0f);
    const float rsx = fmaf(sx, ca,  SQ2 * sa);   // sx*ca - sy*sa
    const float rsy = fmaf(sx, sa, -SQ2 * ca);   // sx*sa + sy*ca
    const float rdx = -2.0f * SQ2 * sa;
    const float rdy =  2.0f * SQ2 * ca;

    // pixel space: p = (g + 1) * 0.5 * (512-1)
    float Ax = (rsx + 1.0f) * 255.5f, Bx = rdx * 255.5f;
    float Ay = (rsy + 1.0f) * 255.5f, By = rdy * 255.5f;

    // Axis swap (wave-uniform: all lanes share the angle): sample the
    // transposed image when |sa| > |ca| so the row step per lane is
    // min(|sa|,|ca|) <= 0.707 -> fewer distinct cache lines per gather.
    const float* base = img;
    if (use_t && fabsf(sa) > fabsf(ca)) {
        float tmp;
        tmp = Ax; Ax = Ay; Ay = tmp;
        tmp = Bx; Bx = By; By = tmp;
        base = imgT;
    }

    // Clip sampled t = s/256 to where the ray can touch the image
    // (any bilinear corner in-bounds requires p in (-1, 512) on both axes).
    // Skipped samples contribute exactly 0.0 in the reference sum.
    float t0 = 0.0f, t1 = 255.0f / 256.0f;
    bool ok = true;
    if (fabsf(Bx) > 1e-9f) {
        const float ra = (-1.0f - Ax) / Bx, rb = (512.0f - Ax) / Bx;
        t0 = fmaxf(t0, fminf(ra, rb));
        t1 = fminf(t1, fmaxf(ra, rb));
    } else if (Ax < -1.0f || Ax > 512.0f) ok = false;
    if (fabsf(By) > 1e-9f) {
        const float ra = (-1.0f - Ay) / By, rb = (512.0f - Ay) / By;
        t0 = fmaxf(t0, fminf(ra, rb));
        t1 = fminf(t1, fmaxf(ra, rb));
    } else if (Ay < -1.0f || Ay > 512.0f) ok = false;

    float acc = 0.0f;
    if (ok && t0 <= t1) {
        const int s0 = max(0, (int)(t0 * 256.0f) - 1);        // conservative
        const int s1 = min(S_N - 1, (int)(t1 * 256.0f) + 1);  // +-1 margin
        for (int s = s0; s <= s1; ++s) {
            const float t = (float)s * (1.0f / 256.0f);
            const float x = fmaf(t, Bx, Ax);
            const float y = fmaf(t, By, Ay);
            const float xf = floorf(x), yf = floorf(y);
            const float fx = x - xf, fy = y - yf;
            const int ix = (int)xf, iy = (int)yf;

            // weights, zeroed for out-of-bounds corners (branchless)
            float wx0 = 1.0f - fx, wx1 = fx;
            float wy0 = 1.0f - fy, wy1 = fy;
            wx0 = ((unsigned)ix       < 512u) ? wx0 : 0.0f;
            wx1 = ((unsigned)(ix + 1) < 512u) ? wx1 : 0.0f;
            wy0 = ((unsigned)iy       < 512u) ? wy0 : 0.0f;
            wy1 = ((unsigned)(iy + 1) < 512u) ? wy1 : 0.0f;

            // clamped addresses: loads always in-bounds
            const int ix0 = min(max(ix, 0), 511);
            const int ix1 = min(max(ix + 1, 0), 511);
            const int iy0 = min(max(iy, 0), 511);
            const int iy1 = min(max(iy + 1, 0), 511);
            const float* r0 = base + (iy0 << 9);
            const float* r1 = base + (iy1 << 9);
            const float v00 = r0[ix0], v10 = r0[ix1];
            const float v01 = r1[ix0], v11 = r1[ix1];

            acc = fmaf(fmaf(v10, wx1, v00 * wx0), wy0, acc);
            acc = fmaf(fmaf(v11, wx1, v01 * wx0), wy1, acc);
        }
    }

    // intens[a][d] / S, then flip both axes
    out[(511 - a) * 512 + (511 - d)] = acc * (1.0f / 256.0f);
}

extern "C" void kernel_launch(void* const* d_in, const int* in_sizes, int n_in,
                              void* d_out, int out_size, void* d_ws, size_t ws_size,
                              hipStream_t stream) {
    const float* img = (const float*)d_in[0];
    float* out = (float*)d_out;
    float* imgT = (float*)d_ws;
    const int use_t = (ws_size >= (size_t)(IMG * IMG * sizeof(float))) ? 1 : 0;

    if (use_t) {
        transpose_kernel<<<256, 256, 0, stream>>>(img, imgT);
    }
    radon_fwd<<<(A_N * D_N) / 256, 256, 0, stream>>>(
        img, use_t ? imgT : img, use_t, out);
}

// Round 3
// 172.106 us; speedup vs baseline: 1.3389x; 1.3389x over previous
//
#include <hip/hip_runtime.h>
#include <math.h>

// Problem constants (setup_inputs is fixed): 512x512 fp32 image, A=512 angles,
// D=512 detectors, S=256 sampling points, step_size=1.
#define IMG 512
#define A_N 512
#define D_N 512
#define S_N 256

// ---------------------------------------------------------------------------
// Zero the output (capture-safe replacement for hipMemsetAsync).
// ---------------------------------------------------------------------------
__global__ __launch_bounds__(256)
void zero_kernel(float* __restrict__ out, int n) {
    const int i = blockIdx.x * 256 + threadIdx.x;
    if (i < n) out[i] = 0.0f;
}

// ---------------------------------------------------------------------------
// Build packed corner arrays:
//   pack [y][x] = (im(y,x),  im(y,x+1c),  im(y+1c,x),  im(y+1c,x+1c))
//   packT[X][Y] = same with im replaced by imT(r,c)=im(c,r)
// so bilinear needs ONE aligned float4 gather instead of four dword gathers.
// (+1c = clamped to 511; pack base index is clamped to [0,510] at sample time.)
// packT written via LDS transpose so both writes are coalesced.
// ---------------------------------------------------------------------------
__global__ __launch_bounds__(256)
void pack_kernel(const float* __restrict__ im,
                 float4* __restrict__ pack, float4* __restrict__ packT) {
    __shared__ float4 lds[32][33];          // +1 pad: no bank conflicts
    const int bx = blockIdx.x & 15;         // 16x16 tiles of 32x32
    const int by = blockIdx.x >> 4;
    const int tx = threadIdx.x & 31;
    const int ty = threadIdx.x >> 5;        // 0..7
    const int x0 = bx * 32, y0 = by * 32;
    #pragma unroll
    for (int i = 0; i < 4; ++i) {
        const int y = y0 + ty + i * 8;
        const int x = x0 + tx;
        const int xp = min(x + 1, IMG - 1);
        const int yp = min(y + 1, IMG - 1);
        const float a = im[y * IMG + x];
        const float b = im[y * IMG + xp];
        const float c = im[yp * IMG + x];
        const float d = im[yp * IMG + xp];
        pack[y * IMG + x] = make_float4(a, b, c, d);
        // packT[x][y] needs (a, c, b, d); stage transposed in LDS
        lds[tx][ty + i * 8] = make_float4(a, c, b, d);
    }
    __syncthreads();
    #pragma unroll
    for (int i = 0; i < 4; ++i) {
        const int r = ty + i * 8;           // local X
        packT[(x0 + r) * IMG + (y0 + tx)] = lds[r][tx];
    }
}

// ---------------------------------------------------------------------------
// Radon forward. 2 threads per output (s-range split in half for occupancy);
// lanes map to consecutive detectors -> wave gather footprint is a 64-px
// segment along the rotated detector axis (row step <= 0.707 after axis swap).
// One float4 gather per bilinear sample.
// ---------------------------------------------------------------------------
__global__ __launch_bounds__(256)
void radon_packed(const float4* __restrict__ pack, const float4* __restrict__ packT,
                  float* __restrict__ out) {
    const int tid  = blockIdx.x * 256 + threadIdx.x;
    const int d    = tid & (D_N - 1);
    const int a    = (tid >> 9) & (A_N - 1);
    const int half = tid >> 18;             // 0 or 1: sample-range half

    const float PI  = 3.14159265358979323846f;
    const float SQ2 = 1.41421356237309504880f;

    const float ang = fmaf((float)a, PI / 511.0f, PI * 0.5f);
    float sa, ca;
    sincosf(ang, &sa, &ca);

    const float sx  = fmaf((float)d, 2.0f / 511.0f, -1.0f);
    const float rsx = fmaf(sx, ca,  SQ2 * sa);
    const float rsy = fmaf(sx, sa, -SQ2 * ca);
    const float rdx = -2.0f * SQ2 * sa;
    const float rdy =  2.0f * SQ2 * ca;

    float Ax = (rsx + 1.0f) * 255.5f, Bx = rdx * 255.5f;
    float Ay = (rsy + 1.0f) * 255.5f, By = rdy * 255.5f;

    // Axis swap (wave-uniform): row step per lane = min(|sa|,|ca|) <= 0.707
    const float4* base = pack;
    if (fabsf(sa) > fabsf(ca)) {
        float t;
        t = Ax; Ax = Ay; Ay = t;
        t = Bx; Bx = By; By = t;
        base = packT;
    }

    // Clip t=s/256 to where any bilinear corner can be in-bounds
    // (p in (-1,512) on both axes). Skipped samples are exactly 0.
    float t0 = 0.0f, t1 = 255.0f / 256.0f;
    bool ok = true;
    if (fabsf(Bx) > 1e-9f) {
        const float ra = (-1.0f - Ax) / Bx, rb = (512.0f - Ax) / Bx;
        t0 = fmaxf(t0, fminf(ra, rb));
        t1 = fminf(t1, fmaxf(ra, rb));
    } else if (Ax < -1.0f || Ax > 512.0f) ok = false;
    if (fabsf(By) > 1e-9f) {
        const float ra = (-1.0f - Ay) / By, rb = (512.0f - Ay) / By;
        t0 = fmaxf(t0, fminf(ra, rb));
        t1 = fminf(t1, fmaxf(ra, rb));
    } else if (Ay < -1.0f || Ay > 512.0f) ok = false;

    float acc = 0.0f;
    if (ok && t0 <= t1) {
        int s0 = max(0, (int)(t0 * 256.0f) - 1);          // conservative +-1
        int s1 = min(S_N - 1, (int)(t1 * 256.0f) + 1);
        s0 = max(s0, half * (S_N / 2));                   // this thread's half
        s1 = min(s1, half * (S_N / 2) + (S_N / 2) - 1);
        for (int s = s0; s <= s1; ++s) {
            const float t = (float)s * (1.0f / 256.0f);
            const float x = fmaf(t, Bx, Ax);
            const float y = fmaf(t, By, Ay);
            const float xf = floorf(x), yf = floorf(y);
            const float fx = x - xf, fy = y - yf;
            const int ix = (int)xf, iy = (int)yf;

            // pack base index in [0,510]; remap weights for edge cases:
            //  ix in [0,510]: (w0,w1)=(1-fx,fx)
            //  ix==-1: value img[0] sits in slot0 -> (fx, 0)
            //  ix==511: value img[511] sits in slot1 -> (0, 1-fx)
            //  else OOB: (0,0)
            const int p = min(max(ix, 0), IMG - 2);
            const int q = min(max(iy, 0), IMG - 2);
            const bool xin = (unsigned)ix <= 510u;
            const bool yin = (unsigned)iy <= 510u;
            const float wx0 = xin ? (1.0f - fx) : ((ix == -1)  ? fx : 0.0f);
            const float wx1 = xin ? fx          : ((ix == 511) ? (1.0f - fx) : 0.0f);
            const float wy0 = yin ? (1.0f - fy) : ((iy == -1)  ? fy : 0.0f);
            const float wy1 = yin ? fy          : ((iy == 511) ? (1.0f - fy) : 0.0f);

            const float4 P = base[(q << 9) + p];
            const float top = fmaf(P.y, wx1, P.x * wx0);
            const float bot = fmaf(P.w, wx1, P.z * wx0);
            acc = fmaf(top, wy0, fmaf(bot, wy1, acc));
        }
    }

    atomicAdd(&out[(511 - a) * 512 + (511 - d)], acc * (1.0f / 256.0f));
}

// ---------------------------------------------------------------------------
// Fallback (ws too small for packed arrays): direct 4-gather version.
// ---------------------------------------------------------------------------
__global__ __launch_bounds__(256)
void radon_direct(const float* __restrict__ img, float* __restrict__ out) {
    const int tid = blockIdx.x * 256 + threadIdx.x;
    const int d = tid & (D_N - 1);
    const int a = tid >> 9;
    const float PI  = 3.14159265358979323846f;
    const float SQ2 = 1.41421356237309504880f;
    const float ang = fmaf((float)a, PI / 511.0f, PI * 0.5f);
    float sa, ca;
    sincosf(ang, &sa, &ca);
    const float sx  = fmaf((float)d, 2.0f / 511.0f, -1.0f);
    const float Ax = (fmaf(sx, ca,  SQ2 * sa) + 1.0f) * 255.5f;
    const float Ay = (fmaf(sx, sa, -SQ2 * ca) + 1.0f) * 255.5f;
    const float Bx = -2.0f * SQ2 * sa * 255.5f;
    const float By =  2.0f * SQ2 * ca * 255.5f;
    float acc = 0.0f;
    for (int s = 0; s < S_N; ++s) {
        const float t = (float)s * (1.0f / 256.0f);
        const float x = fmaf(t, Bx, Ax);
        const float y = fmaf(t, By, Ay);
        const float xf = floorf(x), yf = floorf(y);
        const float fx = x - xf, fy = y - yf;
        const int ix = (int)xf, iy = (int)yf;
        float wx0 = 1.0f - fx, wx1 = fx, wy0 = 1.0f - fy, wy1 = fy;
        wx0 = ((unsigned)ix       < 512u) ? wx0 : 0.0f;
        wx1 = ((unsigned)(ix + 1) < 512u) ? wx1 : 0.0f;
        wy0 = ((unsigned)iy       < 512u) ? wy0 : 0.0f;
        wy1 = ((unsigned)(iy + 1) < 512u) ? wy1 : 0.0f;
        const int ix0 = min(max(ix, 0), 511), ix1 = min(max(ix + 1, 0), 511);
        const int iy0 = min(max(iy, 0), 511), iy1 = min(max(iy + 1, 0), 511);
        const float* r0 = img + (iy0 << 9);
        const float* r1 = img + (iy1 << 9);
        acc = fmaf(fmaf(r0[ix1], wx1, r0[ix0] * wx0), wy0, acc);
        acc = fmaf(fmaf(r1[ix1], wx1, r1[ix0] * wx0), wy1, acc);
    }
    out[(511 - a) * 512 + (511 - d)] = acc * (1.0f / 256.0f);
}

extern "C" void kernel_launch(void* const* d_in, const int* in_sizes, int n_in,
                              void* d_out, int out_size, void* d_ws, size_t ws_size,
                              hipStream_t stream) {
    const float* img = (const float*)d_in[0];
    float* out = (float*)d_out;
    const size_t packBytes = (size_t)IMG * IMG * sizeof(float4);  // 4 MB

    if (ws_size >= 2 * packBytes) {
        float4* pack  = (float4*)d_ws;
        float4* packT = pack + (size_t)IMG * IMG;
        pack_kernel<<<256, 256, 0, stream>>>(img, pack, packT);
        zero_kernel<<<(A_N * D_N) / 256, 256, 0, stream>>>(out, A_N * D_N);
        radon_packed<<<(A_N * D_N * 2) / 256, 256, 0, stream>>>(pack, packT, out);
    } else {
        radon_direct<<<(A_N * D_N) / 256, 256, 0, stream>>>(img, out);
    }
}

// Round 5
// 150.032 us; speedup vs baseline: 1.5359x; 1.1471x over previous
//
#include <hip/hip_runtime.h>
#include <math.h>

// Problem constants (setup_inputs is fixed): 512x512 fp32 image, A=512 angles,
// D=512 detectors, S=256 sampling points, step_size=1.
#define IMG 512
#define A_N 512
#define D_N 512
#define S_N 256
#define PAD 4      // zero border in px around the packed image
#define PW  528    // padded pack stride (entries per row); valid q,p in [0,PW)

// 8-byte packed bilinear corner cell: (v00,v10,v01,v11) as fp16.
struct H4 { _Float16 v00, v10, v01, v11; };

// zero-extended image read (grid_sample padding_mode='zeros' semantics)
__device__ __forceinline__ float imz(const float* __restrict__ im, int y, int x) {
    return ((unsigned)y < 512u && (unsigned)x < 512u) ? im[(y << 9) + x] : 0.0f;
}

// ---------------------------------------------------------------------------
// Build fp16 packed-corner arrays over the ZERO-PADDED image (border PAD px):
//   pack [q][p] = (imz(y,x), imz(y,x+1), imz(y+1,x), imz(y+1,x+1)),
//   packT       = same on the transposed image,  with y=q-PAD, x=p-PAD.
// Plain bilinear weights on these entries == reference's zeros-masked gather
// (up to fp16 value rounding) — no boundary weight remap at sample time.
// ---------------------------------------------------------------------------
__global__ __launch_bounds__(256)
void pack_fp16(const float* __restrict__ im,
               H4* __restrict__ pack, H4* __restrict__ packT) {
    const int bx = blockIdx.x % 17, by = blockIdx.x / 17;   // 17x17 tiles of 32x32
    const int tx = threadIdx.x & 31, ty0 = threadIdx.x >> 5;
    const int p = bx * 32 + tx;
    if (p >= PW) return;
    const int x = p - PAD;
    #pragma unroll
    for (int i = 0; i < 4; ++i) {
        const int q = by * 32 + ty0 + i * 8;
        if (q >= PW) continue;
        const int y = q - PAD;
        {   // pack: image
            H4 e;
            e.v00 = (_Float16)imz(im, y, x);
            e.v10 = (_Float16)imz(im, y, x + 1);
            e.v01 = (_Float16)imz(im, y + 1, x);
            e.v11 = (_Float16)imz(im, y + 1, x + 1);
            pack[q * PW + p] = e;
        }
        {   // packT: transposed image imT(r,c)=im(c,r)
            H4 e;
            e.v00 = (_Float16)imz(im, x, y);
            e.v10 = (_Float16)imz(im, x + 1, y);
            e.v01 = (_Float16)imz(im, x, y + 1);
            e.v11 = (_Float16)imz(im, x + 1, y + 1);
            packT[q * PW + p] = e;
        }
    }
}

// ---------------------------------------------------------------------------
// Radon forward. Block = (angle, 64-detector group); its 4 waves take the 4
// s-quarters (2-unrolled: 2 gathers in flight per wave). Lanes = consecutive
// detectors. blockIdx swizzled so each XCD (blk%8) gets a 64-angle band ->
// its hot pack slice (~2.2 MB) fits the 4 MB per-XCD L2.
// ---------------------------------------------------------------------------
__global__ __launch_bounds__(256)
void radon_fp16(const H4* __restrict__ pack, const H4* __restrict__ packT,
                float* __restrict__ out) {
    const int blk  = blockIdx.x;
    const int a    = ((blk & 7) << 6) | ((blk >> 3) & 63);  // XCD k -> angles [64k,64k+64)
    const int dg   = blk >> 9;                              // detector group 0..7
    const int lane = threadIdx.x & 63;
    const int h    = threadIdx.x >> 6;                      // s-quarter 0..3
    const int d    = dg * 64 + lane;

    const float PI  = 3.14159265358979323846f;
    const float SQ2 = 1.41421356237309504880f;

    const float ang = fmaf((float)a, PI / 511.0f, PI * 0.5f);
    float sa, ca;
    sincosf(ang, &sa, &ca);

    const float sx = fmaf((float)d, 2.0f / 511.0f, -1.0f);
    float Ax = (fmaf(sx, ca,  SQ2 * sa) + 1.0f) * 255.5f;
    float Ay = (fmaf(sx, sa, -SQ2 * ca) + 1.0f) * 255.5f;
    float Bx = -2.0f * SQ2 * sa * 255.5f;
    float By =  2.0f * SQ2 * ca * 255.5f;

    // Axis swap (wave-uniform): y step per s becomes min(|sa|,|ca|) component
    const H4* base = pack;
    if (fabsf(sa) > fabsf(ca)) {
        float t;
        t = Ax; Ax = Ay; Ay = t;
        t = Bx; Bx = By; By = t;
        base = packT;
    }

    // Clip t=s/256 to x,y in (-1,512); skipped samples contribute exactly 0.
    // |Bx| >= ~511 after swap (fast axis); By may be ~0.
    float t0 = 0.0f, t1 = 255.0f / 256.0f;
    bool ok = true;
    {
        const float ra = (-1.0f - Ax) / Bx, rb = (512.0f - Ax) / Bx;
        t0 = fmaxf(t0, fminf(ra, rb));
        t1 = fminf(t1, fmaxf(ra, rb));
    }
    if (fabsf(By) > 1e-9f) {
        const float ra = (-1.0f - Ay) / By, rb = (512.0f - Ay) / By;
        t0 = fmaxf(t0, fminf(ra, rb));
        t1 = fminf(t1, fmaxf(ra, rb));
    } else if (Ay < -1.0f || Ay > 512.0f) ok = false;

    float acc = 0.0f;
    if (ok && t0 <= t1) {
        int s0 = max(0, (int)(t0 * 256.0f) - 1);          // +-1 sample margin:
        int s1 = min(S_N - 1, (int)(t1 * 256.0f) + 1);    // overshoot < PAD-1 px
        s0 = max(s0, h * 64);                             // this wave's quarter
        s1 = min(s1, h * 64 + 63);
        Ax += (float)PAD;                                 // shift into padded coords
        Ay += (float)PAD;

        float acc2 = 0.0f;
        int s = s0;
        for (; s < s1; s += 2) {                          // 2 independent samples
            const float tA = (float)s       * (1.0f / 256.0f);
            const float tB = (float)(s + 1) * (1.0f / 256.0f);
            const float xA = fmaf(tA, Bx, Ax), yA = fmaf(tA, By, Ay);
            const float xB = fmaf(tB, Bx, Ax), yB = fmaf(tB, By, Ay);
            const float xfA = floorf(xA), yfA = floorf(yA);
            const float xfB = floorf(xB), yfB = floorf(yB);
            const int ixA = min(max((int)xfA, 0), PW - 2);
            const int iyA = min(max((int)yfA, 0), PW - 2);
            const int ixB = min(max((int)xfB, 0), PW - 2);
            const int iyB = min(max((int)yfB, 0), PW - 2);
            const H4 PA = base[iyA * PW + ixA];           // both loads issue
            const H4 PB = base[iyB * PW + ixB];           // before first use
            const float fxA = xA - xfA, fyA = yA - yfA;
            const float fxB = xB - xfB, fyB = yB - yfB;
            const float topA = fmaf((float)PA.v10, fxA, (float)PA.v00 * (1.0f - fxA));
            const float botA = fmaf((float)PA.v11, fxA, (float)PA.v01 * (1.0f - fxA));
            acc  = fmaf(botA - topA, fyA, topA + acc);    // top*(1-fy)+bot*fy
            const float topB = fmaf((float)PB.v10, fxB, (float)PB.v00 * (1.0f - fxB));
            const float botB = fmaf((float)PB.v11, fxB, (float)PB.v01 * (1.0f - fxB));
            acc2 = fmaf(botB - topB, fyB, topB + acc2);
        }
        if (s == s1) {                                    // odd tail
            const float t = (float)s * (1.0f / 256.0f);
            const float x = fmaf(t, Bx, Ax), y = fmaf(t, By, Ay);
            const float xf = floorf(x), yf = floorf(y);
            const int ix = min(max((int)xf, 0), PW - 2);
            const int iy = min(max((int)yf, 0), PW - 2);
            const H4 P = base[iy * PW + ix];
            const float fx = x - xf, fy = y - yf;
            const float top = fmaf((float)P.v10, fx, (float)P.v00 * (1.0f - fx));
            const float bot = fmaf((float)P.v11, fx, (float)P.v01 * (1.0f - fx));
            acc = fmaf(bot - top, fy, top + acc);
        }
        acc += acc2;
    }

    // Reduce the 4 s-quarters across the block's 4 waves; one coalesced write.
    __shared__ float red[256];
    red[threadIdx.x] = acc;
    __syncthreads();
    if (threadIdx.x < 64) {
        const float v = (red[threadIdx.x] + red[threadIdx.x + 64] +
                         red[threadIdx.x + 128] + red[threadIdx.x + 192]) * (1.0f / 256.0f);
        const int dd = dg * 64 + threadIdx.x;
        out[(511 - a) * 512 + (511 - dd)] = v;            // flip both axes
    }
}

// ---------------------------------------------------------------------------
// Fallback (ws too small): direct 4-gather version.
// ---------------------------------------------------------------------------
__global__ __launch_bounds__(256)
void radon_direct(const float* __restrict__ img, float* __restrict__ out) {
    const int tid = blockIdx.x * 256 + threadIdx.x;
    const int d = tid & (D_N - 1);
    const int a = tid >> 9;
    const float PI  = 3.14159265358979323846f;
    const float SQ2 = 1.41421356237309504880f;
    const float ang = fmaf((float)a, PI / 511.0f, PI * 0.5f);
    float sa, ca;
    sincosf(ang, &sa, &ca);
    const float sx = fmaf((float)d, 2.0f / 511.0f, -1.0f);
    const float Ax = (fmaf(sx, ca,  SQ2 * sa) + 1.0f) * 255.5f;
    const float Ay = (fmaf(sx, sa, -SQ2 * ca) + 1.0f) * 255.5f;
    const float Bx = -2.0f * SQ2 * sa * 255.5f;
    const float By =  2.0f * SQ2 * ca * 255.5f;
    float acc = 0.0f;
    for (int s = 0; s < S_N; ++s) {
        const float t = (float)s * (1.0f / 256.0f);
        const float x = fmaf(t, Bx, Ax);
        const float y = fmaf(t, By, Ay);
        const float xf = floorf(x), yf = floorf(y);
        const float fx = x - xf, fy = y - yf;
        const int ix = (int)xf, iy = (int)yf;
        float wx0 = 1.0f - fx, wx1 = fx, wy0 = 1.0f - fy, wy1 = fy;
        wx0 = ((unsigned)ix       < 512u) ? wx0 : 0.0f;
        wx1 = ((unsigned)(ix + 1) < 512u) ? wx1 : 0.0f;
        wy0 = ((unsigned)iy       < 512u) ? wy0 : 0.0f;
        wy1 = ((unsigned)(iy + 1) < 512u) ? wy1 : 0.0f;
        const int ix0 = min(max(ix, 0), 511), ix1 = min(max(ix + 1, 0), 511);
        const int iy0 = min(max(iy, 0), 511), iy1 = min(max(iy + 1, 0), 511);
        const float* r0 = img + (iy0 << 9);
        const float* r1 = img + (iy1 << 9);
        acc = fmaf(fmaf(r0[ix1], wx1, r0[ix0] * wx0), wy0, acc);
        acc = fmaf(fmaf(r1[ix1], wx1, r1[ix0] * wx0), wy1, acc);
    }
    out[(511 - a) * 512 + (511 - d)] = acc * (1.0f / 256.0f);
}

extern "C" void kernel_launch(void* const* d_in, const int* in_sizes, int n_in,
                              void* d_out, int out_size, void* d_ws, size_t ws_size,
                              hipStream_t stream) {
    const float* img = (const float*)d_in[0];
    float* out = (float*)d_out;
    const size_t packBytes = (size_t)PW * PW * sizeof(H4);   // ~2.23 MB each

    if (ws_size >= 2 * packBytes) {
        H4* pack  = (H4*)d_ws;
        H4* packT = pack + (size_t)PW * PW;
        pack_fp16<<<17 * 17, 256, 0, stream>>>(img, pack, packT);
        radon_fp16<<<4096, 256, 0, stream>>>(pack, packT, out);
    } else {
        radon_direct<<<(A_N * D_N) / 256, 256, 0, stream>>>(img, out);
    }
}

// Round 6
// 139.593 us; speedup vs baseline: 1.6508x; 1.0748x over previous
//
#include <hip/hip_runtime.h>
#include <math.h>

// Problem constants (setup_inputs is fixed): 512x512 fp32 image, A=512 angles,
// D=512 detectors, S=256 sampling points, step_size=1.
#define IMG 512
#define A_N 512
#define D_N 512
#define S_N 256
#define PAD 8      // zero border: covers +-1-sample clip margin (<=5.7 px) with room
#define PW  528    // padded pack stride (entries per row); valid q,p in [0,PW)

// 8-byte packed bilinear corner cell: (v00,v10,v01,v11) as fp16.
struct H4 { _Float16 v00, v10, v01, v11; };

// zero-extended image read (grid_sample padding_mode='zeros' semantics)
__device__ __forceinline__ float imz(const float* __restrict__ im, int y, int x) {
    return ((unsigned)y < 512u && (unsigned)x < 512u) ? im[(y << 9) + x] : 0.0f;
}

// ---------------------------------------------------------------------------
// Build fp16 packed-corner arrays over the ZERO-PADDED image (border PAD px):
//   pack [q][p] = (imz(y,x), imz(y,x+1), imz(y+1,x), imz(y+1,x+1)), y=q-PAD...
//   packT       = same on the transposed image.
// All global reads AND writes coalesced; packT goes through an LDS transpose
// (the R4/R5 version read columns -> 64 lines/wave-load -> ~60 us; this fixes it).
// ---------------------------------------------------------------------------
__global__ __launch_bounds__(256)
void pack_fp16(const float* __restrict__ im,
               H4* __restrict__ pack, H4* __restrict__ packT) {
    __shared__ H4 ldsT[32][33];                 // +1 pad: conflict-free
    const int bx = blockIdx.x % 17, by = blockIdx.x / 17;   // 17x17 tiles of 32
    const int tx = threadIdx.x & 31, ty0 = threadIdx.x >> 5;
    const int p = bx * 32 + tx;                 // output col (may exceed PW-1)
    const int x = p - PAD;
    #pragma unroll
    for (int i = 0; i < 4; ++i) {
        const int ty = ty0 + i * 8;
        const int q = by * 32 + ty;
        const int y = q - PAD;
        const float a = imz(im, y, x);          // coalesced (x = lane-consec)
        const float b = imz(im, y, x + 1);
        const float c = imz(im, y + 1, x);
        const float d = imz(im, y + 1, x + 1);
        if (p < PW && q < PW) {
            H4 e; e.v00 = (_Float16)a; e.v10 = (_Float16)b;
                  e.v01 = (_Float16)c; e.v11 = (_Float16)d;
            pack[q * PW + p] = e;               // coalesced 8B store
        }
        // transposed-image corners at (row=x, col=y): (a, c, b, d)
        H4 eT; eT.v00 = (_Float16)a; eT.v10 = (_Float16)c;
               eT.v01 = (_Float16)b; eT.v11 = (_Float16)d;
        ldsT[tx][ty] = eT;
    }
    __syncthreads();
    #pragma unroll
    for (int i = 0; i < 4; ++i) {
        const int r  = ty0 + i * 8;
        const int qT = bx * 32 + r;             // swapped tile coords
        const int pT = by * 32 + tx;
        if (qT < PW && pT < PW)
            packT[qT * PW + pT] = ldsT[r][tx];  // coalesced 8B store
    }
}

// ---------------------------------------------------------------------------
// Radon forward. Block = (angle, 64-detector group); each of the 4 waves takes
// a quarter of the CLIPPED s-range (balanced). s-loop unrolled x4: 4 gathers
// in flight, 4 independent accumulators. No clamps: PAD=8 provably covers the
// +-1-sample margin overshoot (<= 2*2.83 px), so padded coords stay in
// [1.3, 525.7] subset [0, PW-2]. XCD swizzle: blk%8 -> 64-angle band -> hot
// pack slice (~2.2 MB) is L2-resident per XCD.
// ---------------------------------------------------------------------------
__global__ __launch_bounds__(256, 8)
void radon_fp16(const H4* __restrict__ pack, const H4* __restrict__ packT,
                float* __restrict__ out) {
    const int blk  = blockIdx.x;
    const int a    = ((blk & 7) << 6) | ((blk >> 3) & 63);
    const int dg   = blk >> 9;
    const int lane = threadIdx.x & 63;
    const int h    = threadIdx.x >> 6;          // wave id 0..3
    const int d    = dg * 64 + lane;

    const float PI  = 3.14159265358979323846f;
    const float SQ2 = 1.41421356237309504880f;

    const float ang = fmaf((float)a, PI / 511.0f, PI * 0.5f);
    float sa, ca;
    sincosf(ang, &sa, &ca);

    const float sx = fmaf((float)d, 2.0f / 511.0f, -1.0f);
    float Ax = (fmaf(sx, ca,  SQ2 * sa) + 1.0f) * 255.5f;
    float Ay = (fmaf(sx, sa, -SQ2 * ca) + 1.0f) * 255.5f;
    float Bx = -2.0f * SQ2 * sa * 255.5f;
    float By =  2.0f * SQ2 * ca * 255.5f;

    // Axis swap (wave-uniform): fast axis -> x, row step <= 0.707/sample-px
    const H4* base = pack;
    if (fabsf(sa) > fabsf(ca)) {
        float t;
        t = Ax; Ax = Ay; Ay = t;
        t = Bx; Bx = By; By = t;
        base = packT;
    }

    // Clip t=s/256 to x,y in (-1,512); skipped samples contribute exactly 0.
    float t0 = 0.0f, t1 = 255.0f / 256.0f;
    bool ok = true;
    {
        const float ra = (-1.0f - Ax) / Bx, rb = (512.0f - Ax) / Bx;
        t0 = fmaxf(t0, fminf(ra, rb));
        t1 = fminf(t1, fmaxf(ra, rb));
    }
    if (fabsf(By) > 1e-9f) {
        const float ra = (-1.0f - Ay) / By, rb = (512.0f - Ay) / By;
        t0 = fmaxf(t0, fminf(ra, rb));
        t1 = fminf(t1, fmaxf(ra, rb));
    } else if (Ay < -1.0f || Ay > 512.0f) ok = false;

    float acc0 = 0.0f, acc1 = 0.0f, acc2 = 0.0f, acc3 = 0.0f;
    if (ok && t0 <= t1) {
        const int s0  = max(0, (int)(t0 * 256.0f) - 1);       // +-1 margin
        const int s1  = min(S_N - 1, (int)(t1 * 256.0f) + 1);
        const int len = s1 - s0 + 1;
        if (len > 0) {
            const int qn  = (len + 3) >> 2;                   // balanced quarters
            const int ws0 = s0 + h * qn;
            const int ws1 = min(ws0 + qn - 1, s1);

            // x(s) = Ax' + s*dBx in padded coords
            const float dBx = Bx * (1.0f / 256.0f);
            const float dBy = By * (1.0f / 256.0f);
            Ax += (float)PAD;
            Ay += (float)PAD;

            int s = ws0;
            for (; s + 3 <= ws1; s += 4) {
                // 4 addresses, then 4 loads in flight, then 4 interps
                const float x0 = fmaf((float)(s    ), dBx, Ax);
                const float y0 = fmaf((float)(s    ), dBy, Ay);
                const float x1 = fmaf((float)(s + 1), dBx, Ax);
                const float y1 = fmaf((float)(s + 1), dBy, Ay);
                const float x2 = fmaf((float)(s + 2), dBx, Ax);
                const float y2 = fmaf((float)(s + 2), dBy, Ay);
                const float x3 = fmaf((float)(s + 3), dBx, Ax);
                const float y3 = fmaf((float)(s + 3), dBy, Ay);
                const int ix0 = (int)x0, iy0 = (int)y0;       // coords > 0
                const int ix1 = (int)x1, iy1 = (int)y1;
                const int ix2 = (int)x2, iy2 = (int)y2;
                const int ix3 = (int)x3, iy3 = (int)y3;
                const H4 P0 = base[iy0 * PW + ix0];
                const H4 P1 = base[iy1 * PW + ix1];
                const H4 P2 = base[iy2 * PW + ix2];
                const H4 P3 = base[iy3 * PW + ix3];
                const float fx0 = x0 - (float)ix0, fy0 = y0 - (float)iy0;
                const float fx1 = x1 - (float)ix1, fy1 = y1 - (float)iy1;
                const float fx2 = x2 - (float)ix2, fy2 = y2 - (float)iy2;
                const float fx3 = x3 - (float)ix3, fy3 = y3 - (float)iy3;
                {
                    const float t_ = fmaf(fx0, (float)P0.v10 - (float)P0.v00, (float)P0.v00);
                    const float b_ = fmaf(fx0, (float)P0.v11 - (float)P0.v01, (float)P0.v01);
                    acc0 = fmaf(fy0, b_ - t_, t_ + acc0);
                }
                {
                    const float t_ = fmaf(fx1, (float)P1.v10 - (float)P1.v00, (float)P1.v00);
                    const float b_ = fmaf(fx1, (float)P1.v11 - (float)P1.v01, (float)P1.v01);
                    acc1 = fmaf(fy1, b_ - t_, t_ + acc1);
                }
                {
                    const float t_ = fmaf(fx2, (float)P2.v10 - (float)P2.v00, (float)P2.v00);
                    const float b_ = fmaf(fx2, (float)P2.v11 - (float)P2.v01, (float)P2.v01);
                    acc2 = fmaf(fy2, b_ - t_, t_ + acc2);
                }
                {
                    const float t_ = fmaf(fx3, (float)P3.v10 - (float)P3.v00, (float)P3.v00);
                    const float b_ = fmaf(fx3, (float)P3.v11 - (float)P3.v01, (float)P3.v01);
                    acc3 = fmaf(fy3, b_ - t_, t_ + acc3);
                }
            }
            for (; s <= ws1; ++s) {                           // tail (<=3)
                const float x = fmaf((float)s, dBx, Ax);
                const float y = fmaf((float)s, dBy, Ay);
                const int ix = (int)x, iy = (int)y;
                const H4 P = base[iy * PW + ix];
                const float fx = x - (float)ix, fy = y - (float)iy;
                const float t_ = fmaf(fx, (float)P.v10 - (float)P.v00, (float)P.v00);
                const float b_ = fmaf(fx, (float)P.v11 - (float)P.v01, (float)P.v01);
                acc0 = fmaf(fy, b_ - t_, t_ + acc0);
            }
        }
    }
    const float acc = (acc0 + acc1) + (acc2 + acc3);

    // Reduce the 4 wave-quarters; one coalesced write. No zero-init needed.
    __shared__ float red[256];
    red[threadIdx.x] = acc;
    __syncthreads();
    if (threadIdx.x < 64) {
        const float v = (red[threadIdx.x] + red[threadIdx.x + 64] +
                         red[threadIdx.x + 128] + red[threadIdx.x + 192]) * (1.0f / 256.0f);
        const int dd = dg * 64 + threadIdx.x;
        out[(511 - a) * 512 + (511 - dd)] = v;                // flip both axes
    }
}

// ---------------------------------------------------------------------------
// Fallback (ws too small): direct 4-gather version.
// ---------------------------------------------------------------------------
__global__ __launch_bounds__(256)
void radon_direct(const float* __restrict__ img, float* __restrict__ out) {
    const int tid = blockIdx.x * 256 + threadIdx.x;
    const int d = tid & (D_N - 1);
    const int a = tid >> 9;
    const float PI  = 3.14159265358979323846f;
    const float SQ2 = 1.41421356237309504880f;
    const float ang = fmaf((float)a, PI / 511.0f, PI * 0.5f);
    float sa, ca;
    sincosf(ang, &sa, &ca);
    const float sx = fmaf((float)d, 2.0f / 511.0f, -1.0f);
    const float Ax = (fmaf(sx, ca,  SQ2 * sa) + 1.0f) * 255.5f;
    const float Ay = (fmaf(sx, sa, -SQ2 * ca) + 1.0f) * 255.5f;
    const float Bx = -2.0f * SQ2 * sa * 255.5f;
    const float By =  2.0f * SQ2 * ca * 255.5f;
    float acc = 0.0f;
    for (int s = 0; s < S_N; ++s) {
        const float t = (float)s * (1.0f / 256.0f);
        const float x = fmaf(t, Bx, Ax);
        const float y = fmaf(t, By, Ay);
        const float xf = floorf(x), yf = floorf(y);
        const float fx = x - xf, fy = y - yf;
        const int ix = (int)xf, iy = (int)yf;
        float wx0 = 1.0f - fx, wx1 = fx, wy0 = 1.0f - fy, wy1 = fy;
        wx0 = ((unsigned)ix       < 512u) ? wx0 : 0.0f;
        wx1 = ((unsigned)(ix + 1) < 512u) ? wx1 : 0.0f;
        wy0 = ((unsigned)iy       < 512u) ? wy0 : 0.0f;
        wy1 = ((unsigned)(iy + 1) < 512u) ? wy1 : 0.0f;
        const int ix0 = min(max(ix, 0), 511), ix1 = min(max(ix + 1, 0), 511);
        const int iy0 = min(max(iy, 0), 511), iy1 = min(max(iy + 1, 0), 511);
        const float* r0 = img + (iy0 << 9);
        const float* r1 = img + (iy1 << 9);
        acc = fmaf(fmaf(r0[ix1], wx1, r0[ix0] * wx0), wy0, acc);
        acc = fmaf(fmaf(r1[ix1], wx1, r1[ix0] * wx0), wy1, acc);
    }
    out[(511 - a) * 512 + (511 - d)] = acc * (1.0f / 256.0f);
}

extern "C" void kernel_launch(void* const* d_in, const int* in_sizes, int n_in,
                              void* d_out, int out_size, void* d_ws, size_t ws_size,
                              hipStream_t stream) {
    const float* img = (const float*)d_in[0];
    float* out = (float*)d_out;
    const size_t packBytes = (size_t)PW * PW * sizeof(H4);   // ~2.23 MB each

    if (ws_size >= 2 * packBytes) {
        H4* pack  = (H4*)d_ws;
        H4* packT = pack + (size_t)PW * PW;
        pack_fp16<<<17 * 17, 256, 0, stream>>>(img, pack, packT);
        radon_fp16<<<4096, 256, 0, stream>>>(pack, packT, out);
    } else {
        radon_direct<<<(A_N * D_N) / 256, 256, 0, stream>>>(img, out);
    }
}

// Round 7
// 133.980 us; speedup vs baseline: 1.7199x; 1.0419x over previous
//
#include <hip/hip_runtime.h>
#include <math.h>

// Problem constants (setup_inputs is fixed): 512x512 fp32 image, A=512 angles,
// D=512 detectors, S=256 sampling points, step_size=1.
#define IMG 512
#define A_N 512
#define D_N 512
#define S_N 256
#define PAD 8      // zero border: covers +-1-sample clip margin (<=5.7 px) with room
#define PW  528    // padded pack stride (entries per row); valid q,p in [0,PW)

// 8-byte packed bilinear corner cell: (v00,v10,v01,v11) as fp16.
struct H4 { _Float16 v00, v10, v01, v11; };

// zero-extended image read (grid_sample padding_mode='zeros' semantics)
__device__ __forceinline__ float imz(const float* __restrict__ im, int y, int x) {
    return ((unsigned)y < 512u && (unsigned)x < 512u) ? im[(y << 9) + x] : 0.0f;
}

// ---------------------------------------------------------------------------
// Build fp16 packed-corner arrays over the ZERO-PADDED image (border PAD px):
//   pack [q][p] = (imz(y,x), imz(y,x+1), imz(y+1,x), imz(y+1,x+1)), y=q-PAD...
//   packT       = same on the transposed image.
// All global reads AND writes coalesced; packT staged through an LDS transpose.
// ---------------------------------------------------------------------------
__global__ __launch_bounds__(256)
void pack_fp16(const float* __restrict__ im,
               H4* __restrict__ pack, H4* __restrict__ packT) {
    __shared__ H4 ldsT[32][33];                 // +1 pad: conflict-free
    const int bx = blockIdx.x % 17, by = blockIdx.x / 17;   // 17x17 tiles of 32
    const int tx = threadIdx.x & 31, ty0 = threadIdx.x >> 5;
    const int p = bx * 32 + tx;                 // output col (may exceed PW-1)
    const int x = p - PAD;
    #pragma unroll
    for (int i = 0; i < 4; ++i) {
        const int ty = ty0 + i * 8;
        const int q = by * 32 + ty;
        const int y = q - PAD;
        const float a = imz(im, y, x);          // coalesced (x = lane-consec)
        const float b = imz(im, y, x + 1);
        const float c = imz(im, y + 1, x);
        const float d = imz(im, y + 1, x + 1);
        if (p < PW && q < PW) {
            H4 e; e.v00 = (_Float16)a; e.v10 = (_Float16)b;
                  e.v01 = (_Float16)c; e.v11 = (_Float16)d;
            pack[q * PW + p] = e;               // coalesced 8B store
        }
        // transposed-image corners at (row=x, col=y): (a, c, b, d)
        H4 eT; eT.v00 = (_Float16)a; eT.v10 = (_Float16)c;
               eT.v01 = (_Float16)b; eT.v11 = (_Float16)d;
        ldsT[tx][ty] = eT;
    }
    __syncthreads();
    #pragma unroll
    for (int i = 0; i < 4; ++i) {
        const int r  = ty0 + i * 8;
        const int qT = bx * 32 + r;             // swapped tile coords
        const int pT = by * 32 + tx;
        if (qT < PW && pT < PW)
            packT[qT * PW + pT] = ldsT[r][tx];  // coalesced 8B store
    }
}

// One bilinear sample's persistent state between load- and compute-phase.
struct Samp { H4 P; float fx, fy; };

__device__ __forceinline__ Samp samp_load(const H4* __restrict__ base,
                                          float Ax, float Ay,
                                          float dBx, float dBy, int s) {
    Samp r;
    const float x = fmaf((float)s, dBx, Ax);    // padded coords, always > 0
    const float y = fmaf((float)s, dBy, Ay);
    const int ix = (int)x, iy = (int)y;
    r.P  = base[iy * PW + ix];
    r.fx = x - (float)ix;
    r.fy = y - (float)iy;
    return r;
}

__device__ __forceinline__ void samp_acc(const Samp& r, float& acc) {
    const float t_ = fmaf(r.fx, (float)r.P.v10 - (float)r.P.v00, (float)r.P.v00);
    const float b_ = fmaf(r.fx, (float)r.P.v11 - (float)r.P.v01, (float)r.P.v01);
    acc = fmaf(r.fy, b_ - t_, t_ + acc);
}

// ---------------------------------------------------------------------------
// Radon forward. Block = (angle, 64-detector group); each of the 4 waves takes
// a quarter of the CLIPPED s-range. Software-pipelined unroll-4: group g+1's
// 4 gathers are issued before group g's interpolation -> 8 loads in flight.
// No coord clamps needed: PAD=8 covers the +-1-sample margin overshoot.
// XCD swizzle: blk%8 -> 64-angle band (hot pack slice ~2.2 MB L2-resident);
// detector groups ordered center-first so long blocks launch early (tail fix).
// ---------------------------------------------------------------------------
__global__ __launch_bounds__(256, 6)
void radon_fp16(const H4* __restrict__ pack, const H4* __restrict__ packT,
                float* __restrict__ out) {
    const int blk  = blockIdx.x;
    const int a    = ((blk & 7) << 6) | ((blk >> 3) & 63);
    const int dg   = (int)((0x70615243u >> ((blk >> 9) * 4)) & 7u); // {3,4,2,5,1,6,0,7}
    const int lane = threadIdx.x & 63;
    const int h    = threadIdx.x >> 6;          // wave id 0..3
    const int d    = dg * 64 + lane;

    const float PI  = 3.14159265358979323846f;
    const float SQ2 = 1.41421356237309504880f;

    const float ang = fmaf((float)a, PI / 511.0f, PI * 0.5f);
    float sa, ca;
    sincosf(ang, &sa, &ca);

    const float sx = fmaf((float)d, 2.0f / 511.0f, -1.0f);
    float Ax = (fmaf(sx, ca,  SQ2 * sa) + 1.0f) * 255.5f;
    float Ay = (fmaf(sx, sa, -SQ2 * ca) + 1.0f) * 255.5f;
    float Bx = -2.0f * SQ2 * sa * 255.5f;
    float By =  2.0f * SQ2 * ca * 255.5f;

    // Axis swap (wave-uniform): fast axis -> x, row step <= 0.707 px/sample-px
    const H4* base = pack;
    if (fabsf(sa) > fabsf(ca)) {
        float t;
        t = Ax; Ax = Ay; Ay = t;
        t = Bx; Bx = By; By = t;
        base = packT;
    }

    // Clip t=s/256 to x,y in (-1,512); skipped samples contribute exactly 0.
    float t0 = 0.0f, t1 = 255.0f / 256.0f;
    bool ok = true;
    {
        const float ra = (-1.0f - Ax) / Bx, rb = (512.0f - Ax) / Bx;
        t0 = fmaxf(t0, fminf(ra, rb));
        t1 = fminf(t1, fmaxf(ra, rb));
    }
    if (fabsf(By) > 1e-9f) {
        const float ra = (-1.0f - Ay) / By, rb = (512.0f - Ay) / By;
        t0 = fmaxf(t0, fminf(ra, rb));
        t1 = fminf(t1, fmaxf(ra, rb));
    } else if (Ay < -1.0f || Ay > 512.0f) ok = false;

    float acc0 = 0.0f, acc1 = 0.0f, acc2 = 0.0f, acc3 = 0.0f;
    if (ok && t0 <= t1) {
        const int s0  = max(0, (int)(t0 * 256.0f) - 1);       // +-1 margin
        const int s1  = min(S_N - 1, (int)(t1 * 256.0f) + 1);
        const int len = s1 - s0 + 1;
        if (len > 0) {
            const int qn  = (len + 3) >> 2;                   // balanced quarters
            const int ws0 = s0 + h * qn;
            const int ws1 = min(ws0 + qn - 1, s1);

            const float dBx = Bx * (1.0f / 256.0f);
            const float dBy = By * (1.0f / 256.0f);
            Ax += (float)PAD;                                 // padded coords
            Ay += (float)PAD;

            int s = ws0;
            const int nFull = (ws1 - ws0 + 1) >> 2;           // full 4-groups
            if (nFull > 0) {
                // prologue: load group 0
                Samp c0 = samp_load(base, Ax, Ay, dBx, dBy, s);
                Samp c1 = samp_load(base, Ax, Ay, dBx, dBy, s + 1);
                Samp c2 = samp_load(base, Ax, Ay, dBx, dBy, s + 2);
                Samp c3 = samp_load(base, Ax, Ay, dBx, dBy, s + 3);
                for (int g = 1; g < nFull; ++g) {
                    // issue next group's 4 gathers...
                    Samp n0 = samp_load(base, Ax, Ay, dBx, dBy, s + 4);
                    Samp n1 = samp_load(base, Ax, Ay, dBx, dBy, s + 5);
                    Samp n2 = samp_load(base, Ax, Ay, dBx, dBy, s + 6);
                    Samp n3 = samp_load(base, Ax, Ay, dBx, dBy, s + 7);
                    // ...then consume the current group (its loads are old)
                    samp_acc(c0, acc0);
                    samp_acc(c1, acc1);
                    samp_acc(c2, acc2);
                    samp_acc(c3, acc3);
                    c0 = n0; c1 = n1; c2 = n2; c3 = n3;
                    s += 4;
                }
                samp_acc(c0, acc0);                           // epilogue
                samp_acc(c1, acc1);
                samp_acc(c2, acc2);
                samp_acc(c3, acc3);
                s += 4;
            }
            for (; s <= ws1; ++s) {                           // tail (<=3)
                Samp r = samp_load(base, Ax, Ay, dBx, dBy, s);
                samp_acc(r, acc0);
            }
        }
    }
    const float acc = (acc0 + acc1) + (acc2 + acc3);

    // Reduce the 4 wave-quarters; one coalesced write.
    __shared__ float red[256];
    red[threadIdx.x] = acc;
    __syncthreads();
    if (threadIdx.x < 64) {
        const float v = (red[threadIdx.x] + red[threadIdx.x + 64] +
                         red[threadIdx.x + 128] + red[threadIdx.x + 192]) * (1.0f / 256.0f);
        const int dd = dg * 64 + threadIdx.x;
        out[(511 - a) * 512 + (511 - dd)] = v;                // flip both axes
    }
}

// ---------------------------------------------------------------------------
// Fallback (ws too small): direct 4-gather version.
// ---------------------------------------------------------------------------
__global__ __launch_bounds__(256)
void radon_direct(const float* __restrict__ img, float* __restrict__ out) {
    const int tid = blockIdx.x * 256 + threadIdx.x;
    const int d = tid & (D_N - 1);
    const int a = tid >> 9;
    const float PI  = 3.14159265358979323846f;
    const float SQ2 = 1.41421356237309504880f;
    const float ang = fmaf((float)a, PI / 511.0f, PI * 0.5f);
    float sa, ca;
    sincosf(ang, &sa, &ca);
    const float sx = fmaf((float)d, 2.0f / 511.0f, -1.0f);
    const float Ax = (fmaf(sx, ca,  SQ2 * sa) + 1.0f) * 255.5f;
    const float Ay = (fmaf(sx, sa, -SQ2 * ca) + 1.0f) * 255.5f;
    const float Bx = -2.0f * SQ2 * sa * 255.5f;
    const float By =  2.0f * SQ2 * ca * 255.5f;
    float acc = 0.0f;
    for (int s = 0; s < S_N; ++s) {
        const float t = (float)s * (1.0f / 256.0f);
        const float x = fmaf(t, Bx, Ax);
        const float y = fmaf(t, By, Ay);
        const float xf = floorf(x), yf = floorf(y);
        const float fx = x - xf, fy = y - yf;
        const int ix = (int)xf, iy = (int)yf;
        float wx0 = 1.0f - fx, wx1 = fx, wy0 = 1.0f - fy, wy1 = fy;
        wx0 = ((unsigned)ix       < 512u) ? wx0 : 0.0f;
        wx1 = ((unsigned)(ix + 1) < 512u) ? wx1 : 0.0f;
        wy0 = ((unsigned)iy       < 512u) ? wy0 : 0.0f;
        wy1 = ((unsigned)(iy + 1) < 512u) ? wy1 : 0.0f;
        const int ix0 = min(max(ix, 0), 511), ix1 = min(max(ix + 1, 0), 511);
        const int iy0 = min(max(iy, 0), 511), iy1 = min(max(iy + 1, 0), 511);
        const float* r0 = img + (iy0 << 9);
        const float* r1 = img + (iy1 << 9);
        acc = fmaf(fmaf(r0[ix1], wx1, r0[ix0] * wx0), wy0, acc);
        acc = fmaf(fmaf(r1[ix1], wx1, r1[ix0] * wx0), wy1, acc);
    }
    out[(511 - a) * 512 + (511 - d)] = acc * (1.0f / 256.0f);
}

extern "C" void kernel_launch(void* const* d_in, const int* in_sizes, int n_in,
                              void* d_out, int out_size, void* d_ws, size_t ws_size,
                              hipStream_t stream) {
    const float* img = (const float*)d_in[0];
    float* out = (float*)d_out;
    const size_t packBytes = (size_t)PW * PW * sizeof(H4);   // ~2.23 MB each

    if (ws_size >= 2 * packBytes) {
        H4* pack  = (H4*)d_ws;
        H4* packT = pack + (size_t)PW * PW;
        pack_fp16<<<17 * 17, 256, 0, stream>>>(img, pack, packT);
        radon_fp16<<<4096, 256, 0, stream>>>(pack, packT, out);
    } else {
        radon_direct<<<(A_N * D_N) / 256, 256, 0, stream>>>(img, out);
    }
}

// Round 8
// 123.213 us; speedup vs baseline: 1.8702x; 1.0874x over previous
//
#include <hip/hip_runtime.h>
#include <math.h>

// Problem constants (setup_inputs is fixed): 512x512 fp32 image, A=512 angles,
// D=512 detectors, S=256 sampling points, step_size=1.
#define IMG 512
#define A_N 512
#define D_N 512
#define S_N 256
#define PAD 8      // zero border: covers +-1-sample clip margin (<=5.7 px)
#define PW  528    // padded pack stride (entries per row)

// 8-byte pre-differenced bilinear cell: (v00, v10-v00, v01, v11-v01) fp16.
// top = v00 + fx*dx0 ; bot = v01 + fx*dx1 ; val = top + fy*(bot-top).
struct H4 { _Float16 v00, dx0, v01, dx1; };

// zero-extended image read (grid_sample padding_mode='zeros' semantics)
__device__ __forceinline__ float imz(const float* __restrict__ im, int y, int x) {
    return ((unsigned)y < 512u && (unsigned)x < 512u) ? im[(y << 9) + x] : 0.0f;
}

// ---------------------------------------------------------------------------
// Build fp16 pre-differenced packed-corner arrays over the ZERO-PADDED image:
//   pack [q][p] from im,  packT[q][p] from im^T,  (y,x) = (q-PAD, p-PAD).
// All global reads AND writes coalesced; packT staged through an LDS transpose.
// ---------------------------------------------------------------------------
__global__ __launch_bounds__(256)
void pack_fp16(const float* __restrict__ im,
               H4* __restrict__ pack, H4* __restrict__ packT) {
    __shared__ H4 ldsT[32][33];                 // +1 pad: conflict-free
    const int bx = blockIdx.x % 17, by = blockIdx.x / 17;   // 17x17 tiles of 32
    const int tx = threadIdx.x & 31, ty0 = threadIdx.x >> 5;
    const int p = bx * 32 + tx;
    const int x = p - PAD;
    #pragma unroll
    for (int i = 0; i < 4; ++i) {
        const int ty = ty0 + i * 8;
        const int q = by * 32 + ty;
        const int y = q - PAD;
        const float a = imz(im, y, x);          // coalesced (x = lane-consec)
        const float b = imz(im, y, x + 1);
        const float c = imz(im, y + 1, x);
        const float d = imz(im, y + 1, x + 1);
        if (p < PW && q < PW) {
            H4 e; e.v00 = (_Float16)a; e.dx0 = (_Float16)(b - a);
                  e.v01 = (_Float16)c; e.dx1 = (_Float16)(d - c);
            pack[q * PW + p] = e;               // coalesced 8B store
        }
        // transposed image: v00=a, v10=c, v01=b, v11=d
        H4 eT; eT.v00 = (_Float16)a; eT.dx0 = (_Float16)(c - a);
               eT.v01 = (_Float16)b; eT.dx1 = (_Float16)(d - b);
        ldsT[tx][ty] = eT;
    }
    __syncthreads();
    #pragma unroll
    for (int i = 0; i < 4; ++i) {
        const int r  = ty0 + i * 8;
        const int qT = bx * 32 + r;             // swapped tile coords
        const int pT = by * 32 + tx;
        if (qT < PW && pT < PW)
            packT[qT * PW + pT] = ldsT[r][tx];  // coalesced 8B store
    }
}

// One bilinear sample's state between load- and compute-phase.
struct Samp { H4 P; float fx, fy; };

__device__ __forceinline__ Samp samp_load(const H4* __restrict__ base,
                                          float Ax, float Ay,
                                          float dBx, float dBy, int s) {
    Samp r;
    const float x = fmaf((float)s, dBx, Ax);    // padded coords, always > 0
    const float y = fmaf((float)s, dBy, Ay);
    const int ix = (int)x, iy = (int)y;
    r.P  = base[iy * PW + ix];
    r.fx = x - (float)ix;
    r.fy = y - (float)iy;
    return r;
}

__device__ __forceinline__ void samp_acc(const Samp& r, float& acc) {
    const float t_ = fmaf(r.fx, (float)r.P.dx0, (float)r.P.v00);  // v_fma_mix
    const float b_ = fmaf(r.fx, (float)r.P.dx1, (float)r.P.v01);
    acc = fmaf(r.fy, b_ - t_, t_ + acc);
}

// ---------------------------------------------------------------------------
// Radon forward. Block = (angle, 64-detector group). Wave lane map is 2-D:
// lane = js*16 + di  (16 detectors x 4 s-phases) -> a wave-gather's footprint
// is a 16px x 11.3px patch (vs a 64px segment), cutting distinct cache lines
// per gather ~1.5x (2x at 45 deg). Each thread walks s = s0+js, s0+js+4, ...
// Phases reduced via shfl_xor(16|32); waves then merge through 64-float LDS.
// Depth-2 software pipeline, 4 samples/group -> 8 gathers in flight.
// No coord clamps: PAD=8 covers the +-1-sample margin overshoot.
// XCD swizzle: blk%8 -> 64-angle band (hot pack slice ~2.2 MB L2-resident);
// detector groups ordered center-first so long blocks launch early.
// ---------------------------------------------------------------------------
__global__ __launch_bounds__(256, 6)
void radon_fp16(const H4* __restrict__ pack, const H4* __restrict__ packT,
                float* __restrict__ out) {
    const int blk  = blockIdx.x;
    const int a    = ((blk & 7) << 6) | ((blk >> 3) & 63);
    const int dg   = (int)((0x70615243u >> ((blk >> 9) * 4)) & 7u); // {3,4,2,5,1,6,0,7}
    const int w    = threadIdx.x >> 6;          // wave id 0..3 -> det subgroup
    const int lane = threadIdx.x & 63;
    const int di   = lane & 15;                 // detector within 16
    const int js   = lane >> 4;                 // s-phase 0..3
    const int d    = dg * 64 + w * 16 + di;

    const float PI  = 3.14159265358979323846f;
    const float SQ2 = 1.41421356237309504880f;

    const float ang = fmaf((float)a, PI / 511.0f, PI * 0.5f);
    float sa, ca;
    sincosf(ang, &sa, &ca);

    const float sx = fmaf((float)d, 2.0f / 511.0f, -1.0f);
    float Ax = (fmaf(sx, ca,  SQ2 * sa) + 1.0f) * 255.5f;
    float Ay = (fmaf(sx, sa, -SQ2 * ca) + 1.0f) * 255.5f;
    float Bx = -2.0f * SQ2 * sa * 255.5f;
    float By =  2.0f * SQ2 * ca * 255.5f;

    // Axis swap (wave-uniform): detector axis -> fast-in-x, ray crosses rows
    const H4* base = pack;
    if (fabsf(sa) > fabsf(ca)) {
        float t;
        t = Ax; Ax = Ay; Ay = t;
        t = Bx; Bx = By; By = t;
        base = packT;
    }

    // Clip t=s/256 to x,y in (-1,512); skipped samples contribute exactly 0.
    float t0 = 0.0f, t1 = 255.0f / 256.0f;
    bool ok = true;
    {
        const float ra = (-1.0f - Ax) / Bx, rb = (512.0f - Ax) / Bx;
        t0 = fmaxf(t0, fminf(ra, rb));
        t1 = fminf(t1, fmaxf(ra, rb));
    }
    if (fabsf(By) > 1e-9f) {
        const float ra = (-1.0f - Ay) / By, rb = (512.0f - Ay) / By;
        t0 = fmaxf(t0, fminf(ra, rb));
        t1 = fminf(t1, fmaxf(ra, rb));
    } else if (Ay < -1.0f || Ay > 512.0f) ok = false;

    float acc0 = 0.0f, acc1 = 0.0f, acc2 = 0.0f, acc3 = 0.0f;
    if (ok && t0 <= t1) {
        const int s0  = max(0, (int)(t0 * 256.0f) - 1);       // +-1 margin
        const int s1  = min(S_N - 1, (int)(t1 * 256.0f) + 1);
        const int m   = s1 - (s0 + js);                       // phase iter count
        const int nk  = (m >= 0) ? ((m >> 2) + 1) : 0;        // s = s0+js+4k

        const float dBx = Bx * (1.0f / 256.0f);
        const float dBy = By * (1.0f / 256.0f);
        Ax += (float)PAD;                                     // padded coords
        Ay += (float)PAD;

        int s = s0 + js;                                      // stride 4
        int k = 0;
        const int nFull = nk >> 2;                            // 4-sample groups
        if (nFull > 0) {
            Samp c0 = samp_load(base, Ax, Ay, dBx, dBy, s);
            Samp c1 = samp_load(base, Ax, Ay, dBx, dBy, s + 4);
            Samp c2 = samp_load(base, Ax, Ay, dBx, dBy, s + 8);
            Samp c3 = samp_load(base, Ax, Ay, dBx, dBy, s + 12);
            for (int g = 1; g < nFull; ++g) {
                Samp n0 = samp_load(base, Ax, Ay, dBx, dBy, s + 16);
                Samp n1 = samp_load(base, Ax, Ay, dBx, dBy, s + 20);
                Samp n2 = samp_load(base, Ax, Ay, dBx, dBy, s + 24);
                Samp n3 = samp_load(base, Ax, Ay, dBx, dBy, s + 28);
                samp_acc(c0, acc0);
                samp_acc(c1, acc1);
                samp_acc(c2, acc2);
                samp_acc(c3, acc3);
                c0 = n0; c1 = n1; c2 = n2; c3 = n3;
                s += 16;
            }
            samp_acc(c0, acc0);
            samp_acc(c1, acc1);
            samp_acc(c2, acc2);
            samp_acc(c3, acc3);
            s += 16;
            k = nFull << 2;
        }
        for (; k < nk; ++k, s += 4) {                         // tail (<=3)
            Samp r = samp_load(base, Ax, Ay, dBx, dBy, s);
            samp_acc(r, acc0);
        }
    }
    float acc = (acc0 + acc1) + (acc2 + acc3);

    // Reduce the 4 s-phases (lanes di, di+16, di+32, di+48) within the wave.
    acc += __shfl_xor(acc, 16);
    acc += __shfl_xor(acc, 32);

    // Merge waves: wave w's lanes 0..15 hold detectors w*16+di.
    __shared__ float red[64];
    if (lane < 16) red[w * 16 + di] = acc;
    __syncthreads();
    if (threadIdx.x < 64) {
        const float v = red[threadIdx.x] * (1.0f / 256.0f);
        const int dd = dg * 64 + threadIdx.x;
        out[(511 - a) * 512 + (511 - dd)] = v;                // flip both axes
    }
}

// ---------------------------------------------------------------------------
// Fallback (ws too small): direct 4-gather version.
// ---------------------------------------------------------------------------
__global__ __launch_bounds__(256)
void radon_direct(const float* __restrict__ img, float* __restrict__ out) {
    const int tid = blockIdx.x * 256 + threadIdx.x;
    const int d = tid & (D_N - 1);
    const int a = tid >> 9;
    const float PI  = 3.14159265358979323846f;
    const float SQ2 = 1.41421356237309504880f;
    const float ang = fmaf((float)a, PI / 511.0f, PI * 0.5f);
    float sa, ca;
    sincosf(ang, &sa, &ca);
    const float sx = fmaf((float)d, 2.0f / 511.0f, -1.0f);
    const float Ax = (fmaf(sx, ca,  SQ2 * sa) + 1.0f) * 255.5f;
    const float Ay = (fmaf(sx, sa, -SQ2 * ca) + 1.0f) * 255.5f;
    const float Bx = -2.0f * SQ2 * sa * 255.5f;
    const float By =  2.0f * SQ2 * ca * 255.5f;
    float acc = 0.0f;
    for (int s = 0; s < S_N; ++s) {
        const float t = (float)s * (1.0f / 256.0f);
        const float x = fmaf(t, Bx, Ax);
        const float y = fmaf(t, By, Ay);
        const float xf = floorf(x), yf = floorf(y);
        const float fx = x - xf, fy = y - yf;
        const int ix = (int)xf, iy = (int)yf;
        float wx0 = 1.0f - fx, wx1 = fx, wy0 = 1.0f - fy, wy1 = fy;
        wx0 = ((unsigned)ix       < 512u) ? wx0 : 0.0f;
        wx1 = ((unsigned)(ix + 1) < 512u) ? wx1 : 0.0f;
        wy0 = ((unsigned)iy       < 512u) ? wy0 : 0.0f;
        wy1 = ((unsigned)(iy + 1) < 512u) ? wy1 : 0.0f;
        const int ix0 = min(max(ix, 0), 511), ix1 = min(max(ix + 1, 0), 511);
        const int iy0 = min(max(iy, 0), 511), iy1 = min(max(iy + 1, 0), 511);
        const float* r0 = img + (iy0 << 9);
        const float* r1 = img + (iy1 << 9);
        acc = fmaf(fmaf(r0[ix1], wx1, r0[ix0] * wx0), wy0, acc);
        acc = fmaf(fmaf(r1[ix1], wx1, r1[ix0] * wx0), wy1, acc);
    }
    out[(511 - a) * 512 + (511 - d)] = acc * (1.0f / 256.0f);
}

extern "C" void kernel_launch(void* const* d_in, const int* in_sizes, int n_in,
                              void* d_out, int out_size, void* d_ws, size_t ws_size,
                              hipStream_t stream) {
    const float* img = (const float*)d_in[0];
    float* out = (float*)d_out;
    const size_t packBytes = (size_t)PW * PW * sizeof(H4);   // ~2.23 MB each

    if (ws_size >= 2 * packBytes) {
        H4* pack  = (H4*)d_ws;
        H4* packT = pack + (size_t)PW * PW;
        pack_fp16<<<17 * 17, 256, 0, stream>>>(img, pack, packT);
        radon_fp16<<<4096, 256, 0, stream>>>(pack, packT, out);
    } else {
        radon_direct<<<(A_N * D_N) / 256, 256, 0, stream>>>(img, out);
    }
}